// Round 8
// baseline (719.047 us; speedup 1.0000x reference)
//
#include <hip/hip_runtime.h>
#include <cstddef>
#include <cstdint>

// SpatialEmbLoss on MI355X.
// H=W=768, 2 images, NC=5 classes, MAX_ID=3 -> 15 (class,id) pairs per image.
// Lovasz hinge via 256-bin error histogram:
//   lov = integral_0^2 jac(t) dt,  jac(t) = 1 - (gts - n_in(t))/(gts + n_out(t))
// Round 8: k_hist was LDS-atomic-serialization-bound (41.8us, VALU 26%): 64
// contiguous px/wave map to ~4-14 distinct bins -> every wave atomic was a
// multi-way SAME-ADDRESS RMW chain (u16 packing made it worse). Now ballot-
// aggregated updates: loop distinct bins (ctz+readlane+ballot), leader does
// one atomicAdd(bin, popcount). u32 bins, 30.7KB LDS.

#define HH 768
#define WW 768
#define NPIX (HH*WW)            // 589824
#define NCL 5
#define MAXID 3
#define PAIRS (NCL*MAXID)       // 15
#define NIMG 2
#define NCH 9                   // 2 emb + 2 sigma + 5 seed channels
#define BINS 256
#define HPXB 2048               // pixels per k_hist block (4/thread @ 512 thr)
#define HNB (NPIX/HPXB)         // 288 blocks per image
#define TX 12                   // pass1 x-tiles (64 cols each)
#define TY 32                   // pass1 y-tiles (24 rows each)
#define XW 64
#define YH 24
#define BPI (TX*TY)             // 384 pass1 blocks per image
#define ANB 64                  // argmin blocks per image
#define APXB (NPIX/ANB)         // 9216 px per argmin block

struct WS {
  // ---------- zero region (zeroed by k_pass1 grid-stride every call) ----------
  alignas(8) unsigned int hall[NIMG][PAIRS][2][BINS];  // [0]=out, [1]=in
  float varsum[NIMG][PAIRS];
  float seedin[NIMG][PAIRS];
  unsigned int lovdone;
  unsigned int zpad[3];
  // ---------- end zero region ----------
  unsigned long long argkey[NIMG][PAIRS];   // ~0 init by pass1 blk0; atomicMin
  float medx[NIMG][PAIRS], medy[NIMG][PAIRS];
  float s0a[NIMG][PAIRS], s1a[NIMG][PAIRS];
  float sm0a[NIMG][PAIRS], sm1a[NIMG][PAIRS];
  float validf[NIMG][PAIRS], cntf[NIMG][PAIRS];
  float lov[NIMG][PAIRS];
  float seedT[NIMG], seedOwn[NIMG];
  unsigned int cnt[NIMG][PAIRS];
  alignas(16) float2 emb[NIMG][NPIX];      // {tanh(p0)+x, tanh(p1)+y}
  unsigned char pridx[NIMG][NPIX];         // pair index 0..14, 255 = none
  // transposed pass1 partials (atomic-free, contiguous reduce reads)
  alignas(64) unsigned short colpart[NIMG][PAIRS][WW][TY];  // [x][yt]
  alignas(64) unsigned short rowpart[NIMG][PAIRS][HH][TX];  // [y][xt]
  float sig0part[NIMG][PAIRS][BPI];
  float sig1part[NIMG][PAIRS][BPI];
  float sTpart[NIMG][BPI];
  float sOpart[NIMG][BPI];
};

__device__ __forceinline__ float basef(int i) {
  // jnp.linspace(0,1,1024)[i]
  return (float)i * (1.0f / 1023.0f);
}
__device__ __forceinline__ int pair_of(int l, int it) {
  return (l >= 1 && l <= NCL && it >= 1 && it <= MAXID) ? (l - 1) * MAXID + (it - 1) : -1;
}
__device__ __forceinline__ float fast_sigmoid(float z) {
  return __fdividef(1.f, 1.f + __expf(-z));
}
__device__ __forceinline__ float fast_tanh(float x) {
  float xc = fminf(fmaxf(x, -15.f), 15.f);
  float e = __expf(2.f * xc);
  return __fdividef(e - 1.f, e + 1.f);
}

// ---------------- pass 1: tile 64x24; LDS hists; transposed partial stores;
//                  also zeroes accumulator region + inits argkeys (no memsets)
__global__ __launch_bounds__(256) void k_pass1(const float* __restrict__ pred,
                                               const int* __restrict__ inst,
                                               const int* __restrict__ lab,
                                               WS* __restrict__ ws) {
  int img = blockIdx.z;
  int xt = blockIdx.x, yt = blockIdx.y;
  int x0 = xt * XW;
  int y0 = yt * YH;
  int tid = threadIdx.x, lane = tid & 63, wv = tid >> 6;

  // distributed zero of accumulator region + argkey init
  {
    const int ZN = (int)(offsetof(WS, argkey) / 4);   // u32 count
    int bid = (blockIdx.z * TY + blockIdx.y) * TX + blockIdx.x;
    int idx = bid * 256 + tid;
    if (idx < ZN) ((unsigned int*)ws)[idx] = 0u;
    if (bid == 0 && tid < NIMG * PAIRS)
      ((unsigned long long*)ws->argkey)[tid] = ~0ULL;
  }

  const float* p = pred + (size_t)img * NCH * NPIX;
  const int* lb = lab + (size_t)img * NPIX;
  const int* ib = inst + (size_t)img * NPIX;

  __shared__ unsigned int lcol[PAIRS][XW];
  __shared__ unsigned int lrow[PAIRS][YH];
  __shared__ float lsig0[PAIRS], lsig1[PAIRS];
  __shared__ float fred0[4], fred1[4];
  for (int k = tid; k < PAIRS * XW; k += 256) ((unsigned int*)lcol)[k] = 0;
  for (int k = tid; k < PAIRS * YH; k += 256) ((unsigned int*)lrow)[k] = 0;
  if (tid < PAIRS) { lsig0[tid] = 0.f; lsig1[tid] = 0.f; }
  __syncthreads();

  int x = x0 + lane;
  float bx = basef(x);
  float t = 0.f, own = 0.f;
#pragma unroll
  for (int i = 0; i < YH / 4; i++) {         // 6 rows per wave
    int y = y0 + wv + 4 * i;
    int pix = y * WW + x;
    int l = lb[pix];
    int it = ib[pix];
    float s, q;
    s = fast_sigmoid(p[4 * NPIX + pix]); q = s * s; t += q; if (l == 1) own += q;
    s = fast_sigmoid(p[5 * NPIX + pix]); q = s * s; t += q; if (l == 2) own += q;
    s = fast_sigmoid(p[6 * NPIX + pix]); q = s * s; t += q; if (l == 3) own += q;
    s = fast_sigmoid(p[7 * NPIX + pix]); q = s * s; t += q; if (l == 4) own += q;
    s = fast_sigmoid(p[8 * NPIX + pix]); q = s * s; t += q; if (l == 5) own += q;
    float e0 = fast_tanh(p[0 * NPIX + pix]) + bx;
    float e1 = fast_tanh(p[1 * NPIX + pix]) + basef(y);
    ws->emb[img][pix] = make_float2(e0, e1);
    int pr = pair_of(l, it);
    ws->pridx[img][pix] = (unsigned char)(pr >= 0 ? pr : 255);
    if (pr >= 0) {
      atomicAdd(&lcol[pr][lane], 1u);
      atomicAdd(&lrow[pr][y - y0], 1u);
      atomicAdd(&lsig0[pr], p[2 * NPIX + pix]);
      atomicAdd(&lsig1[pr], p[3 * NPIX + pix]);
    }
  }
  // seed scalars: wave reduce -> LDS
  for (int o = 32; o; o >>= 1) { t += __shfl_down(t, o); own += __shfl_down(own, o); }
  if (lane == 0) { fred0[wv] = t; fred1[wv] = own; }
  __syncthreads();

  // transposed partial flush (plain stores; byte-granular writes are safe)
  int bi = yt * TX + xt;                     // 0..BPI-1 within image
  for (int k = tid; k < PAIRS * XW; k += 256) {
    int pp = k >> 6, c = k & 63;
    ws->colpart[img][pp][x0 + c][yt] = (unsigned short)lcol[pp][c];
  }
  for (int k = tid; k < PAIRS * YH; k += 256) {
    int pp = k / YH, r = k % YH;
    ws->rowpart[img][pp][y0 + r][xt] = (unsigned short)lrow[pp][r];
  }
  if (tid < PAIRS) {
    ws->sig0part[img][tid][bi] = lsig0[tid];
    ws->sig1part[img][tid][bi] = lsig1[tid];
  }
  if (tid == 0) {
    ws->sTpart[img][bi] = fred0[0] + fred0[1] + fred0[2] + fred0[3];
    ws->sOpart[img][bi] = fred1[0] + fred1[1] + fred1[2] + fred1[3];
  }
}

// ---------------- pass 2: medians (transposed-partial reduce + block scan),
//                  sigma means, cnt, validf, seed totals
__global__ __launch_bounds__(256) void k_medoid(WS* __restrict__ ws) {
  int img = blockIdx.x / PAIRS, p = blockIdx.x % PAIRS;
  int tid = threadIdx.x, lane = tid & 63, wv = tid >> 6;
  __shared__ unsigned int pref[256];
  __shared__ int cross;
  __shared__ float fr0[4], fr1[4];
  unsigned int c = 0;
  int res[2];
#pragma unroll
  for (int h = 0; h < 2; h++) {
    unsigned int v[3];
#pragma unroll
    for (int j = 0; j < 3; j++) {
      int cc = tid * 3 + j;      // col or row index 0..767
      unsigned int s = 0;
      if (h == 0) {              // 32 contiguous u16 = 16 u32
        const unsigned int* w = (const unsigned int*)ws->colpart[img][p][cc];
#pragma unroll
        for (int i = 0; i < TY / 2; i++) { unsigned int u = w[i]; s += (u & 0xFFFFu) + (u >> 16); }
      } else {                   // 12 contiguous u16 = 6 u32
        const unsigned int* w = (const unsigned int*)ws->rowpart[img][p][cc];
#pragma unroll
        for (int i = 0; i < TX / 2; i++) { unsigned int u = w[i]; s += (u & 0xFFFFu) + (u >> 16); }
      }
      v[j] = s;
    }
    unsigned int s3 = v[0] + v[1] + v[2];
    pref[tid] = s3;
    __syncthreads();
    for (int d = 1; d < 256; d <<= 1) {
      unsigned int tv = (tid >= d) ? pref[tid - d] : 0u;
      __syncthreads();
      pref[tid] += tv;
      __syncthreads();
    }
    c = pref[255];
    unsigned int target = (c > 0) ? (((c - 1u) >> 1) + 1u) : 1u;
    if (tid == 0) cross = 0;
    __syncthreads();
    unsigned int inc = pref[tid];
    unsigned int exc = inc - s3;
    if (inc >= target && exc < target) {
      int j = (exc + v[0] >= target) ? 0 : ((exc + v[0] + v[1] >= target) ? 1 : 2);
      cross = tid * 3 + j;
    }
    __syncthreads();
    res[h] = cross;
    __syncthreads();
  }
  // sigma sums over 384 contiguous partials
  float s0 = 0.f, s1 = 0.f;
  for (int b = tid; b < BPI; b += 256) { s0 += ws->sig0part[img][p][b]; s1 += ws->sig1part[img][p][b]; }
  for (int o = 32; o; o >>= 1) { s0 += __shfl_down(s0, o); s1 += __shfl_down(s1, o); }
  if (lane == 0) { fr0[wv] = s0; fr1[wv] = s1; }
  __syncthreads();
  if (tid == 0) {
    float sig0 = fr0[0] + fr0[1] + fr0[2] + fr0[3];
    float sig1 = fr1[0] + fr1[1] + fr1[2] + fr1[3];
    float vf = (c > 0) ? 1.f : 0.f;
    float cf = (c > 0) ? (float)c : 1.f;
    float sm0 = sig0 / cf, sm1 = sig1 / cf;
    ws->cnt[img][p] = c;
    ws->medx[img][p] = basef(res[0]);
    ws->medy[img][p] = basef(res[1]);
    ws->sm0a[img][p] = sm0;
    ws->sm1a[img][p] = sm1;
    ws->s0a[img][p] = __expf(10.f * sm0);
    ws->s1a[img][p] = __expf(10.f * sm1);
    ws->validf[img][p] = vf;
    ws->cntf[img][p] = cf;
  }
  __syncthreads();
  if (p == 0) {      // seed totals, once per image
    float a = 0.f, o2 = 0.f;
    for (int b = tid; b < BPI; b += 256) { a += ws->sTpart[img][b]; o2 += ws->sOpart[img][b]; }
    for (int o = 32; o; o >>= 1) { a += __shfl_down(a, o); o2 += __shfl_down(o2, o); }
    if (lane == 0) { fr0[wv] = a; fr1[wv] = o2; }
    __syncthreads();
    if (tid == 0) {
      ws->seedT[img] = fr0[0] + fr0[1] + fr0[2] + fr0[3];
      ws->seedOwn[img] = fr1[0] + fr1[1] + fr1[2] + fr1[3];
    }
  }
}

// ---------------- pass 3: medoid argmin; 64 blocks/img -> shallow global chains
__global__ __launch_bounds__(256) void k_argmin(WS* __restrict__ ws) {
  int img = blockIdx.y;
  __shared__ unsigned long long skey[PAIRS];
  __shared__ float smx[PAIRS], smy[PAIRS];
  if (threadIdx.x < PAIRS) {
    skey[threadIdx.x] = ~0ULL;
    smx[threadIdx.x] = ws->medx[img][threadIdx.x];
    smy[threadIdx.x] = ws->medy[img][threadIdx.x];
  }
  __syncthreads();
  int base = blockIdx.x * APXB;
#pragma unroll
  for (int i = 0; i < APXB / 1024; i++) {    // 9 iters x 4 px
    int px0 = base + i * 1024 + threadIdx.x * 4;
    uchar4 pr4 = *(const uchar4*)(ws->pridx[img] + px0);
    int y = px0 / WW;
    int x0 = px0 - y * WW;
    float by = basef(y);
#pragma unroll
    for (int k = 0; k < 4; k++) {
      int pr = (k == 0) ? pr4.x : (k == 1) ? pr4.y : (k == 2) ? pr4.z : pr4.w;
      if (pr != 255) {
        int pix = px0 + k;
        float dx = basef(x0 + k) - smx[pr];
        float dy = by - smy[pr];
        float d = dx * dx + dy * dy;
        unsigned long long key = ((unsigned long long)__float_as_uint(d) << 32) | (unsigned int)pix;
        atomicMin(&skey[pr], key);
      }
    }
  }
  __syncthreads();
  if (threadIdx.x < PAIRS && skey[threadIdx.x] != ~0ULL)
    atomicMin(&ws->argkey[img][threadIdx.x], skey[threadIdx.x]);
}

// ---------------- pass 4 (heavy): ONE pixel pass, all 15 pairs/px.
// Ballot-aggregated LDS histogram updates (distinct-bin loop, leader atomic).
__global__ __launch_bounds__(512) void k_hist(const float* __restrict__ pred,
                                              WS* __restrict__ ws) {
  int img = blockIdx.y;
  int tid = threadIdx.x, lane = tid & 63;
  __shared__ unsigned int h32[PAIRS * 2 * BINS];   // 30720 B, u32 bins
  __shared__ float lvar[PAIRS], lseed[PAIRS];
  __shared__ float lm0[PAIRS], lm1[PAIRS];
  for (int k = tid; k < PAIRS * 2 * BINS; k += 512) h32[k] = 0;
  if (tid < PAIRS) {
    lvar[tid] = 0.f; lseed[tid] = 0.f;
    lm0[tid] = ws->sm0a[img][tid]; lm1[tid] = ws->sm1a[img][tid];
  }
  __syncthreads();

  // per-pair constants (uniform loads -> compiler scalarizes)
  float cxr[PAIRS], cyr[PAIRS], S0r[PAIRS], S1r[PAIRS];
#pragma unroll
  for (int p = 0; p < PAIRS; p++) {
    unsigned long long key = ws->argkey[img][p];
    int imin = (int)(key & 0xffffffffu);
    cxr[p] = basef(imin % WW);
    cyr[p] = basef(imin / WW);
    S0r[p] = ws->s0a[img][p];
    S1r[p] = ws->s1a[img][p];
  }
  const float* pb = pred + (size_t)img * NCH * NPIX;
  const float* embb = (const float*)ws->emb[img];
  const unsigned char* prb = ws->pridx[img];
  int base = blockIdx.x * HPXB;

#pragma unroll
  for (int i = 0; i < HPXB / 512; i++) {       // 4 px/thread
    int pix = base + i * 512 + tid;
    float2 e = *(const float2*)(embb + 2 * pix);
    int pp = prb[pix];
    float dOwn = 0.f;
#pragma unroll
    for (int p = 0; p < PAIRS; p++) {
      float dx = e.x - cxr[p];
      float dy = e.y - cyr[p];
      float q = dx * dx * S0r[p] + dy * dy * S1r[p];
      float d = __expf(-q);
      bool m = (pp == p);
      dOwn = m ? d : dOwn;
      int ib = (int)fminf(d * 256.f, 255.f);   // out-bin; in-hist: 511-ib
      int hidx = p * 512 + (ib ^ (m ? 511 : 0));
      // wave-aggregate: one atomic per DISTINCT hidx in the wave
      unsigned long long todo = __ballot(1);
      while (todo) {
        int leader = __builtin_ctzll(todo);
        int lidx = __builtin_amdgcn_readlane(hidx, leader);
        unsigned long long eq = __ballot(hidx == lidx);
        if (lane == leader)
          atomicAdd(&h32[lidx], (unsigned int)__builtin_popcountll(eq));
        todo &= ~eq;
      }
    }
    if (pp != 255) {                            // fused var + seed_in (own pair)
      float g0 = pb[2 * NPIX + pix] - lm0[pp];
      float g1 = pb[3 * NPIX + pix] - lm1[pp];
      atomicAdd(&lvar[pp], g0 * g0 + g1 * g1);
      float sd = fast_sigmoid(pb[(4 + pp / MAXID) * NPIX + pix]) - dOwn;
      atomicAdd(&lseed[pp], sd * sd);
    }
  }
  __syncthreads();
  // packed u64 flush of adjacent u32 bins; skip zeros
  unsigned long long* gh = (unsigned long long*)&ws->hall[img][0][0][0];
  for (int k = tid; k < PAIRS * 2 * BINS / 2; k += 512) {
    unsigned int lo = h32[2 * k], hi = h32[2 * k + 1];
    if (lo | hi) {
      unsigned long long v = (unsigned long long)lo | ((unsigned long long)hi << 32);
      atomicAdd(&gh[k], v);
    }
  }
  if (tid < PAIRS) {
    if (lvar[tid] != 0.f) atomicAdd(&ws->varsum[img][tid], lvar[tid]);
    if (lseed[tid] != 0.f) atomicAdd(&ws->seedin[img][tid], lseed[tid]);
  }
}

// ---------------- pass 5: lovasz (parallel suffix scan) + (last block) final combine
__global__ __launch_bounds__(256) void k_lovasz(WS* __restrict__ ws, float* __restrict__ out) {
  int b = blockIdx.x / PAIRS, p = blockIdx.x % PAIRS;
  unsigned int gts = ws->cnt[b][p];
  int tid = threadIdx.x;
  float lv = 0.f;
  __shared__ unsigned int sin_s[BINS], sout_s[BINS];
  if (gts != 0) {
    sin_s[tid] = ws->hall[b][p][1][tid];
    sout_s[tid] = ws->hall[b][p][0][tid];
    __syncthreads();
    for (int d = 1; d < BINS; d <<= 1) {     // inclusive suffix scan
      unsigned int a = (tid + d < BINS) ? sin_s[tid + d] : 0u;
      unsigned int c = (tid + d < BINS) ? sout_s[tid + d] : 0u;
      __syncthreads();
      sin_s[tid] += a; sout_s[tid] += c;
      __syncthreads();
    }
    float gtsf = (float)gts;
    float js = 0.f;
    if (tid >= 1) {
      unsigned int Sin = sin_s[tid], Sout = sout_s[tid];
      js = 1.f - (float)(gts - Sin) / (gtsf + (float)Sout);
    }
    for (int o = 32; o; o >>= 1) js += __shfl_down(js, o);
    __shared__ float wsum[4];
    if ((tid & 63) == 0) wsum[tid >> 6] = js;
    __syncthreads();
    if (tid == 0)
      lv = (2.f / BINS) * (0.5f + wsum[0] + wsum[1] + wsum[2] + wsum[3]);
  }
  __shared__ int amLast;
  if (tid == 0) {
    atomicExch(&ws->lov[b][p], lv);           // device-scope publish (G16)
    __threadfence();
    unsigned int old = atomicAdd(&ws->lovdone, 1u);
    amLast = (old == NIMG * PAIRS - 1);
  }
  __syncthreads();
  if (amLast) {
    __shared__ float rl[NIMG], rv[NIMG], rs[NIMG], ro[NIMG];
    if (tid < NIMG) { rl[tid] = 0.f; rv[tid] = 0.f; rs[tid] = 0.f; ro[tid] = 0.f; }
    __syncthreads();
    if (tid < NIMG * PAIRS) {                 // 30 CONCURRENT atomic reads
      int bb = tid / PAIRS, pp = tid % PAIRS;
      float vf = ws->validf[bb][pp];
      float lvv = atomicAdd(&ws->lov[bb][pp], 0.f);  // same-kernel cross-XCD read
      atomicAdd(&rl[bb], vf * lvv);
      atomicAdd(&rv[bb], vf * ws->varsum[bb][pp] / (ws->cntf[bb][pp] * 2.f));
      atomicAdd(&rs[bb], vf * ws->seedin[bb][pp]);
      atomicAdd(&ro[bb], vf);
    }
    __syncthreads();
    if (tid == 0) {
      float tot = 0.f;
      for (int bb = 0; bb < NIMG; bb++) {
        float objs = ro[bb] < 1.f ? 1.f : ro[bb];
        float seed_bg = ws->seedT[bb] - ws->seedOwn[bb];
        float seed_loss = (seed_bg + rs[bb]) / (float)NPIX;
        tot += rl[bb] / objs + 10.f * rv[bb] / objs + seed_loss;
      }
      out[0] = tot * 0.5f;
    }
  }
}

extern "C" void kernel_launch(void* const* d_in, const int* in_sizes, int n_in,
                              void* d_out, int out_size, void* d_ws, size_t ws_size,
                              hipStream_t stream) {
  const float* pred = (const float*)d_in[0];
  const int* inst = (const int*)d_in[1];
  const int* lab = (const int*)d_in[2];
  WS* ws = (WS*)d_ws;

  k_pass1<<<dim3(TX, TY, NIMG), 256, 0, stream>>>(pred, inst, lab, ws);
  k_medoid<<<dim3(NIMG * PAIRS), 256, 0, stream>>>(ws);
  k_argmin<<<dim3(ANB, NIMG), 256, 0, stream>>>(ws);
  k_hist<<<dim3(HNB, NIMG), 512, 0, stream>>>(pred, ws);
  k_lovasz<<<dim3(NIMG * PAIRS), 256, 0, stream>>>(ws, (float*)d_out);
}

// Round 9
// 79.701 us; speedup vs baseline: 9.0218x; 9.0218x over previous
//
#include <hip/hip_runtime.h>
#include <cstddef>
#include <cstdint>

// SpatialEmbLoss on MI355X.
// H=W=768, 2 images, NC=5 classes, MAX_ID=3 -> 15 (class,id) pairs per image.
// Lovasz hinge via 256-bin error histogram:
//   lov = integral_0^2 jac(t) dt,  jac(t) = 1 - (gts - n_in(t))/(gts + n_out(t))
// Round 9: revert r8 ballot (random emb -> ~50 distinct bins/wave -> 16x blowup).
// k_hist: direct u32 LDS atomics; ONE float4/px record {e0,e1,sd_own,pridx};
// 512thr x 1024 blocks = 4/CU (100% wave occupancy); var term moved to pass1/
// medoid via sum(sig^2) identity; 8-way sharded global hall (flush depth 64);
// seed partials in 64 slots (depth 8), reduced+published in k_lovasz.

#define HH 768
#define WW 768
#define NPIX (HH*WW)            // 589824
#define NCL 5
#define MAXID 3
#define PAIRS (NCL*MAXID)       // 15
#define NIMG 2
#define NCH 9                   // 2 emb + 2 sigma + 5 seed channels
#define BINS 256
#define NSH 8                   // hall shards
#define HPXB 1152               // pixels per k_hist block
#define HNB (NPIX/HPXB)         // 512 blocks per image -> 1024 total = 4/CU
#define TX 12                   // pass1 x-tiles (64 cols each)
#define TY 32                   // pass1 y-tiles (24 rows each)
#define XW 64
#define YH 24
#define BPI (TX*TY)             // 384 pass1 blocks per image
#define ANB 64                  // argmin blocks per image
#define APXB (NPIX/ANB)         // 9216 px per argmin block

struct WS {
  // ---------- zero region (zeroed by k_pass1 grid-stride every call) ----------
  alignas(8) unsigned int hall8[NSH][NIMG][PAIRS][2][BINS];  // 491520 B
  float seedpart[NIMG][PAIRS][64];                           // 7680 B
  unsigned int lovdone;
  unsigned int zpad0;
  // ---------- end zero region ----------
  unsigned long long argkey[NIMG][PAIRS];   // ~0 init by pass1 blk0; atomicMin
  float varsum[NIMG][PAIRS];                // finalized by k_medoid
  float seedin[NIMG][PAIRS];                // published by k_lovasz (atomicExch)
  float medx[NIMG][PAIRS], medy[NIMG][PAIRS];
  float s0a[NIMG][PAIRS], s1a[NIMG][PAIRS];
  float sm0a[NIMG][PAIRS], sm1a[NIMG][PAIRS];
  float validf[NIMG][PAIRS], cntf[NIMG][PAIRS];
  float lov[NIMG][PAIRS];
  float seedT[NIMG], seedOwn[NIMG];
  unsigned int cnt[NIMG][PAIRS];
  alignas(16) float4 emb4[NIMG][NPIX];     // {e0, e1, sigmoid(seed_own), pridx bits}
  unsigned char pridx[NIMG][NPIX];         // pair index 0..14, 255 = none (argmin)
  // transposed pass1 partials (atomic-free, contiguous reduce reads)
  alignas(64) unsigned short colpart[NIMG][PAIRS][WW][TY];  // [x][yt]
  alignas(64) unsigned short rowpart[NIMG][PAIRS][HH][TX];  // [y][xt]
  float sig0part[NIMG][PAIRS][BPI];
  float sig1part[NIMG][PAIRS][BPI];
  float sq0part[NIMG][PAIRS][BPI];
  float sq1part[NIMG][PAIRS][BPI];
  float sTpart[NIMG][BPI];
  float sOpart[NIMG][BPI];
};

__device__ __forceinline__ float basef(int i) {
  // jnp.linspace(0,1,1024)[i]
  return (float)i * (1.0f / 1023.0f);
}
__device__ __forceinline__ int pair_of(int l, int it) {
  return (l >= 1 && l <= NCL && it >= 1 && it <= MAXID) ? (l - 1) * MAXID + (it - 1) : -1;
}
__device__ __forceinline__ float fast_sigmoid(float z) {
  return __fdividef(1.f, 1.f + __expf(-z));
}
__device__ __forceinline__ float fast_tanh(float x) {
  float xc = fminf(fmaxf(x, -15.f), 15.f);
  float e = __expf(2.f * xc);
  return __fdividef(e - 1.f, e + 1.f);
}

// ---------------- pass 1: tile 64x24; LDS stats; float4 record store;
//                  zeroes accumulator region + inits argkeys (no memset nodes)
__global__ __launch_bounds__(256) void k_pass1(const float* __restrict__ pred,
                                               const int* __restrict__ inst,
                                               const int* __restrict__ lab,
                                               WS* __restrict__ ws) {
  int img = blockIdx.z;
  int xt = blockIdx.x, yt = blockIdx.y;
  int x0 = xt * XW;
  int y0 = yt * YH;
  int tid = threadIdx.x, lane = tid & 63, wv = tid >> 6;

  // distributed zero of accumulator region + argkey init
  {
    const int ZN = (int)(offsetof(WS, argkey) / 4);   // u32 count (124802)
    int bid = (blockIdx.z * TY + blockIdx.y) * TX + blockIdx.x;
    int idx = bid * 256 + tid;
    if (idx < ZN) ((unsigned int*)ws)[idx] = 0u;
    if (bid == 0 && tid < NIMG * PAIRS)
      ((unsigned long long*)ws->argkey)[tid] = ~0ULL;
  }

  const float* p = pred + (size_t)img * NCH * NPIX;
  const int* lb = lab + (size_t)img * NPIX;
  const int* ib = inst + (size_t)img * NPIX;

  __shared__ unsigned int lcol[PAIRS][XW];
  __shared__ unsigned int lrow[PAIRS][YH];
  __shared__ float lsig0[PAIRS], lsig1[PAIRS], lsq0[PAIRS], lsq1[PAIRS];
  __shared__ float fred0[4], fred1[4];
  for (int k = tid; k < PAIRS * XW; k += 256) ((unsigned int*)lcol)[k] = 0;
  for (int k = tid; k < PAIRS * YH; k += 256) ((unsigned int*)lrow)[k] = 0;
  if (tid < PAIRS) { lsig0[tid] = 0.f; lsig1[tid] = 0.f; lsq0[tid] = 0.f; lsq1[tid] = 0.f; }
  __syncthreads();

  int x = x0 + lane;
  float bx = basef(x);
  float t = 0.f, own = 0.f;
#pragma unroll
  for (int i = 0; i < YH / 4; i++) {         // 6 rows per wave
    int y = y0 + wv + 4 * i;
    int pix = y * WW + x;
    int l = lb[pix];
    int it = ib[pix];
    float s, q, sdown = 0.f;
    s = fast_sigmoid(p[4 * NPIX + pix]); q = s * s; t += q; if (l == 1) { own += q; sdown = s; }
    s = fast_sigmoid(p[5 * NPIX + pix]); q = s * s; t += q; if (l == 2) { own += q; sdown = s; }
    s = fast_sigmoid(p[6 * NPIX + pix]); q = s * s; t += q; if (l == 3) { own += q; sdown = s; }
    s = fast_sigmoid(p[7 * NPIX + pix]); q = s * s; t += q; if (l == 4) { own += q; sdown = s; }
    s = fast_sigmoid(p[8 * NPIX + pix]); q = s * s; t += q; if (l == 5) { own += q; sdown = s; }
    float e0 = fast_tanh(p[0 * NPIX + pix]) + bx;
    float e1 = fast_tanh(p[1 * NPIX + pix]) + basef(y);
    int pr = pair_of(l, it);
    float4 rec;
    rec.x = e0; rec.y = e1; rec.z = sdown;
    rec.w = __int_as_float(pr >= 0 ? pr : 255);
    ws->emb4[img][pix] = rec;
    ws->pridx[img][pix] = (unsigned char)(pr >= 0 ? pr : 255);
    if (pr >= 0) {
      float g0 = p[2 * NPIX + pix];
      float g1 = p[3 * NPIX + pix];
      atomicAdd(&lcol[pr][lane], 1u);
      atomicAdd(&lrow[pr][y - y0], 1u);
      atomicAdd(&lsig0[pr], g0);
      atomicAdd(&lsig1[pr], g1);
      atomicAdd(&lsq0[pr], g0 * g0);
      atomicAdd(&lsq1[pr], g1 * g1);
    }
  }
  // seed scalars: wave reduce -> LDS
  for (int o = 32; o; o >>= 1) { t += __shfl_down(t, o); own += __shfl_down(own, o); }
  if (lane == 0) { fred0[wv] = t; fred1[wv] = own; }
  __syncthreads();

  // transposed partial flush (plain stores)
  int bi = yt * TX + xt;                     // 0..BPI-1 within image
  for (int k = tid; k < PAIRS * XW; k += 256) {
    int pp = k >> 6, c = k & 63;
    ws->colpart[img][pp][x0 + c][yt] = (unsigned short)lcol[pp][c];
  }
  for (int k = tid; k < PAIRS * YH; k += 256) {
    int pp = k / YH, r = k % YH;
    ws->rowpart[img][pp][y0 + r][xt] = (unsigned short)lrow[pp][r];
  }
  if (tid < PAIRS) {
    ws->sig0part[img][tid][bi] = lsig0[tid];
    ws->sig1part[img][tid][bi] = lsig1[tid];
    ws->sq0part[img][tid][bi] = lsq0[tid];
    ws->sq1part[img][tid][bi] = lsq1[tid];
  }
  if (tid == 0) {
    ws->sTpart[img][bi] = fred0[0] + fred0[1] + fred0[2] + fred0[3];
    ws->sOpart[img][bi] = fred1[0] + fred1[1] + fred1[2] + fred1[3];
  }
}

// ---------------- pass 2: medians (transposed-partial reduce + block scan),
//                  sigma means, varsum (sum-sq identity), cnt, seed totals
__global__ __launch_bounds__(256) void k_medoid(WS* __restrict__ ws) {
  int img = blockIdx.x / PAIRS, p = blockIdx.x % PAIRS;
  int tid = threadIdx.x, lane = tid & 63, wv = tid >> 6;
  __shared__ unsigned int pref[256];
  __shared__ int cross;
  __shared__ float fr0[4], fr1[4], fr2[4], fr3[4];
  unsigned int c = 0;
  int res[2];
#pragma unroll
  for (int h = 0; h < 2; h++) {
    unsigned int v[3];
#pragma unroll
    for (int j = 0; j < 3; j++) {
      int cc = tid * 3 + j;      // col or row index 0..767
      unsigned int s = 0;
      if (h == 0) {              // 32 contiguous u16 = 16 u32
        const unsigned int* w = (const unsigned int*)ws->colpart[img][p][cc];
#pragma unroll
        for (int i = 0; i < TY / 2; i++) { unsigned int u = w[i]; s += (u & 0xFFFFu) + (u >> 16); }
      } else {                   // 12 contiguous u16 = 6 u32
        const unsigned int* w = (const unsigned int*)ws->rowpart[img][p][cc];
#pragma unroll
        for (int i = 0; i < TX / 2; i++) { unsigned int u = w[i]; s += (u & 0xFFFFu) + (u >> 16); }
      }
      v[j] = s;
    }
    unsigned int s3 = v[0] + v[1] + v[2];
    pref[tid] = s3;
    __syncthreads();
    for (int d = 1; d < 256; d <<= 1) {
      unsigned int tv = (tid >= d) ? pref[tid - d] : 0u;
      __syncthreads();
      pref[tid] += tv;
      __syncthreads();
    }
    c = pref[255];
    unsigned int target = (c > 0) ? (((c - 1u) >> 1) + 1u) : 1u;
    if (tid == 0) cross = 0;
    __syncthreads();
    unsigned int inc = pref[tid];
    unsigned int exc = inc - s3;
    if (inc >= target && exc < target) {
      int j = (exc + v[0] >= target) ? 0 : ((exc + v[0] + v[1] >= target) ? 1 : 2);
      cross = tid * 3 + j;
    }
    __syncthreads();
    res[h] = cross;
    __syncthreads();
  }
  // sigma sum / sum-sq over 384 contiguous partials
  float s0 = 0.f, s1 = 0.f, q0 = 0.f, q1 = 0.f;
  for (int b = tid; b < BPI; b += 256) {
    s0 += ws->sig0part[img][p][b]; s1 += ws->sig1part[img][p][b];
    q0 += ws->sq0part[img][p][b];  q1 += ws->sq1part[img][p][b];
  }
  for (int o = 32; o; o >>= 1) {
    s0 += __shfl_down(s0, o); s1 += __shfl_down(s1, o);
    q0 += __shfl_down(q0, o); q1 += __shfl_down(q1, o);
  }
  if (lane == 0) { fr0[wv] = s0; fr1[wv] = s1; fr2[wv] = q0; fr3[wv] = q1; }
  __syncthreads();
  if (tid == 0) {
    float sig0 = fr0[0] + fr0[1] + fr0[2] + fr0[3];
    float sig1 = fr1[0] + fr1[1] + fr1[2] + fr1[3];
    float sq0 = fr2[0] + fr2[1] + fr2[2] + fr2[3];
    float sq1 = fr3[0] + fr3[1] + fr3[2] + fr3[3];
    float vf = (c > 0) ? 1.f : 0.f;
    float cf = (c > 0) ? (float)c : 1.f;
    float sm0 = sig0 / cf, sm1 = sig1 / cf;
    ws->cnt[img][p] = c;
    ws->medx[img][p] = basef(res[0]);
    ws->medy[img][p] = basef(res[1]);
    ws->sm0a[img][p] = sm0;
    ws->sm1a[img][p] = sm1;
    ws->s0a[img][p] = __expf(10.f * sm0);
    ws->s1a[img][p] = __expf(10.f * sm1);
    ws->validf[img][p] = vf;
    ws->cntf[img][p] = cf;
    // sum (sig - sm)^2 = sum sig^2 - cnt*sm^2  (sm is the exact mean)
    ws->varsum[img][p] = (sq0 - cf * sm0 * sm0) + (sq1 - cf * sm1 * sm1);
  }
  __syncthreads();
  if (p == 0) {      // seed totals, once per image
    float a = 0.f, o2 = 0.f;
    for (int b = tid; b < BPI; b += 256) { a += ws->sTpart[img][b]; o2 += ws->sOpart[img][b]; }
    for (int o = 32; o; o >>= 1) { a += __shfl_down(a, o); o2 += __shfl_down(o2, o); }
    if (lane == 0) { fr0[wv] = a; fr1[wv] = o2; }
    __syncthreads();
    if (tid == 0) {
      ws->seedT[img] = fr0[0] + fr0[1] + fr0[2] + fr0[3];
      ws->seedOwn[img] = fr1[0] + fr1[1] + fr1[2] + fr1[3];
    }
  }
}

// ---------------- pass 3: medoid argmin; 64 blocks/img -> shallow global chains
__global__ __launch_bounds__(256) void k_argmin(WS* __restrict__ ws) {
  int img = blockIdx.y;
  __shared__ unsigned long long skey[PAIRS];
  __shared__ float smx[PAIRS], smy[PAIRS];
  if (threadIdx.x < PAIRS) {
    skey[threadIdx.x] = ~0ULL;
    smx[threadIdx.x] = ws->medx[img][threadIdx.x];
    smy[threadIdx.x] = ws->medy[img][threadIdx.x];
  }
  __syncthreads();
  int base = blockIdx.x * APXB;
#pragma unroll
  for (int i = 0; i < APXB / 1024; i++) {    // 9 iters x 4 px
    int px0 = base + i * 1024 + threadIdx.x * 4;
    uchar4 pr4 = *(const uchar4*)(ws->pridx[img] + px0);
    int y = px0 / WW;
    int x0 = px0 - y * WW;
    float by = basef(y);
#pragma unroll
    for (int k = 0; k < 4; k++) {
      int pr = (k == 0) ? pr4.x : (k == 1) ? pr4.y : (k == 2) ? pr4.z : pr4.w;
      if (pr != 255) {
        int pix = px0 + k;
        float dx = basef(x0 + k) - smx[pr];
        float dy = by - smy[pr];
        float d = dx * dx + dy * dy;
        unsigned long long key = ((unsigned long long)__float_as_uint(d) << 32) | (unsigned int)pix;
        atomicMin(&skey[pr], key);
      }
    }
  }
  __syncthreads();
  if (threadIdx.x < PAIRS && skey[threadIdx.x] != ~0ULL)
    atomicMin(&ws->argkey[img][threadIdx.x], skey[threadIdx.x]);
}

// ---------------- pass 4 (heavy): ONE pixel pass, all 15 pairs/px.
// Direct u32 LDS atomics; one float4 record/px; 4 blocks/CU (full occupancy);
// sharded global flush (depth 64) + 64-slot seed partials (depth 8).
__global__ __launch_bounds__(512) void k_hist(WS* __restrict__ ws) {
  int img = blockIdx.y;
  int tid = threadIdx.x;
  __shared__ unsigned int h32[PAIRS * 2 * BINS];   // 30720 B
  __shared__ float lseed[PAIRS];
  for (int k = tid; k < PAIRS * 2 * BINS; k += 512) h32[k] = 0;
  if (tid < PAIRS) lseed[tid] = 0.f;
  __syncthreads();

  // per-pair constants (wave-uniform -> SGPRs)
  float cxr[PAIRS], cyr[PAIRS], S0r[PAIRS], S1r[PAIRS];
#pragma unroll
  for (int p = 0; p < PAIRS; p++) {
    unsigned long long key = ws->argkey[img][p];
    int imin = (int)(key & 0xffffffffu);
    cxr[p] = basef(imin % WW);
    cyr[p] = basef(imin / WW);
    S0r[p] = ws->s0a[img][p];
    S1r[p] = ws->s1a[img][p];
  }
  const float4* eb = ws->emb4[img];
  int base = blockIdx.x * HPXB;

  auto hist_px = [&](float4 v) {
    int pp = __float_as_int(v.w);
    float dOwn = 0.f;
#pragma unroll
    for (int p = 0; p < PAIRS; p++) {
      float dx = v.x - cxr[p];
      float dy = v.y - cyr[p];
      float q = dx * dx * S0r[p] + dy * dy * S1r[p];
      float d = __expf(-q);
      bool m = (pp == p);
      dOwn = m ? d : dOwn;
      int ib2 = (int)fminf(d * 256.f, 255.f);   // out-bin; in-hist: 511-ib
      atomicAdd(&h32[p * 512 + (ib2 ^ (m ? 511 : 0))], 1u);
    }
    if (pp != 255) { float sd = v.z - dOwn; atomicAdd(&lseed[pp], sd * sd); }
  };

  // issue all loads up-front, then compute (MLP)
  float4 vA = eb[base + tid];
  float4 vB = eb[base + 512 + tid];
  float4 vC;
  bool hasC = tid < (HPXB - 1024);
  if (hasC) vC = eb[base + 1024 + tid];
  hist_px(vA);
  hist_px(vB);
  if (hasC) hist_px(vC);
  __syncthreads();

  // packed u64 flush into this block's shard; skip zeros
  unsigned long long* gh = (unsigned long long*)&ws->hall8[blockIdx.x & (NSH - 1)][img][0][0][0];
  for (int k = tid; k < PAIRS * 2 * BINS / 2; k += 512) {
    unsigned int lo = h32[2 * k], hi = h32[2 * k + 1];
    if (lo | hi) {
      unsigned long long v = (unsigned long long)lo | ((unsigned long long)hi << 32);
      atomicAdd(&gh[k], v);
    }
  }
  if (tid < PAIRS && lseed[tid] != 0.f)
    atomicAdd(&ws->seedpart[img][tid][blockIdx.x & 63], lseed[tid]);
}

// ---------------- pass 5: lovasz (shard-summed hists, parallel suffix scan)
//                  + seed reduce + (last block) final combine
__global__ __launch_bounds__(256) void k_lovasz(WS* __restrict__ ws, float* __restrict__ out) {
  int b = blockIdx.x / PAIRS, p = blockIdx.x % PAIRS;
  unsigned int gts = ws->cnt[b][p];
  int tid = threadIdx.x;
  float lv = 0.f;
  __shared__ unsigned int sin_s[BINS], sout_s[BINS];
  if (gts != 0) {
    unsigned int si = 0, so = 0;
#pragma unroll
    for (int s = 0; s < NSH; s++) {
      si += ws->hall8[s][b][p][1][tid];
      so += ws->hall8[s][b][p][0][tid];
    }
    sin_s[tid] = si; sout_s[tid] = so;
    __syncthreads();
    for (int d = 1; d < BINS; d <<= 1) {     // inclusive suffix scan
      unsigned int a = (tid + d < BINS) ? sin_s[tid + d] : 0u;
      unsigned int c = (tid + d < BINS) ? sout_s[tid + d] : 0u;
      __syncthreads();
      sin_s[tid] += a; sout_s[tid] += c;
      __syncthreads();
    }
    float gtsf = (float)gts;
    float js = 0.f;
    if (tid >= 1) {
      unsigned int Sin = sin_s[tid], Sout = sout_s[tid];
      js = 1.f - (float)(gts - Sin) / (gtsf + (float)Sout);
    }
    for (int o = 32; o; o >>= 1) js += __shfl_down(js, o);
    __shared__ float wsum[4];
    if ((tid & 63) == 0) wsum[tid >> 6] = js;
    __syncthreads();
    if (tid == 0)
      lv = (2.f / BINS) * (0.5f + wsum[0] + wsum[1] + wsum[2] + wsum[3]);
  }
  // seed_in reduce over 64 slots (wave 0)
  __shared__ float seedred;
  if (tid < 64) {
    float sv = ws->seedpart[b][p][tid];
    for (int o = 32; o; o >>= 1) sv += __shfl_down(sv, o);
    if (tid == 0) seedred = sv;
  }
  __syncthreads();
  __shared__ int amLast;
  if (tid == 0) {
    atomicExch(&ws->lov[b][p], lv);           // device-scope publish (G16)
    atomicExch(&ws->seedin[b][p], seedred);
    __threadfence();
    unsigned int old = atomicAdd(&ws->lovdone, 1u);
    amLast = (old == NIMG * PAIRS - 1);
  }
  __syncthreads();
  if (amLast) {
    __shared__ float rl[NIMG], rv[NIMG], rs[NIMG], ro[NIMG];
    if (tid < NIMG) { rl[tid] = 0.f; rv[tid] = 0.f; rs[tid] = 0.f; ro[tid] = 0.f; }
    __syncthreads();
    if (tid < NIMG * PAIRS) {                 // 30 CONCURRENT atomic reads
      int bb = tid / PAIRS, pp = tid % PAIRS;
      float vf = ws->validf[bb][pp];
      float lvv = atomicAdd(&ws->lov[bb][pp], 0.f);     // same-kernel cross-XCD read
      float sdv = atomicAdd(&ws->seedin[bb][pp], 0.f);
      atomicAdd(&rl[bb], vf * lvv);
      atomicAdd(&rv[bb], vf * ws->varsum[bb][pp] / (ws->cntf[bb][pp] * 2.f));
      atomicAdd(&rs[bb], vf * sdv);
      atomicAdd(&ro[bb], vf);
    }
    __syncthreads();
    if (tid == 0) {
      float tot = 0.f;
      for (int bb = 0; bb < NIMG; bb++) {
        float objs = ro[bb] < 1.f ? 1.f : ro[bb];
        float seed_bg = ws->seedT[bb] - ws->seedOwn[bb];
        float seed_loss = (seed_bg + rs[bb]) / (float)NPIX;
        tot += rl[bb] / objs + 10.f * rv[bb] / objs + seed_loss;
      }
      out[0] = tot * 0.5f;
    }
  }
}

extern "C" void kernel_launch(void* const* d_in, const int* in_sizes, int n_in,
                              void* d_out, int out_size, void* d_ws, size_t ws_size,
                              hipStream_t stream) {
  const float* pred = (const float*)d_in[0];
  const int* inst = (const int*)d_in[1];
  const int* lab = (const int*)d_in[2];
  WS* ws = (WS*)d_ws;

  k_pass1<<<dim3(TX, TY, NIMG), 256, 0, stream>>>(pred, inst, lab, ws);
  k_medoid<<<dim3(NIMG * PAIRS), 256, 0, stream>>>(ws);
  k_argmin<<<dim3(ANB, NIMG), 256, 0, stream>>>(ws);
  k_hist<<<dim3(HNB, NIMG), 512, 0, stream>>>(ws);
  k_lovasz<<<dim3(NIMG * PAIRS), 256, 0, stream>>>(ws, (float*)d_out);
}